// Round 1
// baseline (248.088 us; speedup 1.0000x reference)
//
#include <hip/hip_runtime.h>
#include <stdint.h>
#include <stddef.h>

// Causal attention fused layer for MI355X (gfx950).
// B=2 T=2048 C=1024 H=16 D=64.
// Pipeline: cvt x -> bf16 | transpose-cvt weights -> bf16 N*K | QKV GEMM (mfma 16x16x32 bf16)
//           | flash attention (4 waves/block, 16 q-rows/wave, KV tile 32) | out GEMM f32.
// Workspace layout (needs >= 48 MB):
//   [0,8MB)   x bf16            (M=4096 x K=1024)
//   [8,16MB)  Wt q,k,v,o bf16   (4 x 1024x1024, transposed N x K)
//   [16,40MB) Q,K,V bf16        (3 x (B,H,T,D)), Q pre-scaled by 0.125*log2(e)
//   [40,48MB) O bf16            (B,T,C)

#define B_SZ 2
#define T_SZ 2048
#define C_SZ 1024
#define H_SZ 16
#define D_SZ 64
#define M_SZ (B_SZ * T_SZ)              // 4096
#define BHTD (B_SZ * H_SZ * T_SZ * D_SZ) // 4194304
#define CC (C_SZ * C_SZ)                 // 1048576

typedef __attribute__((ext_vector_type(8))) __bf16 bf16x8;
typedef __attribute__((ext_vector_type(4))) float f32x4;

__device__ __forceinline__ unsigned short f2bf(float f) {
    union { float f; unsigned u; } v; v.f = f;
    v.u += 0x7fffu + ((v.u >> 16) & 1u);   // round-to-nearest-even
    return (unsigned short)(v.u >> 16);
}

__device__ __forceinline__ void load_lds16(const unsigned short* g, unsigned short* l) {
    // width=16 async global->LDS; LDS dest is wave-uniform base + lane*16.
    __builtin_amdgcn_global_load_lds(
        (const __attribute__((address_space(1))) void*)g,
        (__attribute__((address_space(3))) void*)l, 16, 0, 0);
}

// ---------------- conversion kernels ----------------

__global__ void cvt_x_kernel(const float4* __restrict__ in, ushort4* __restrict__ out, int n4) {
    int stride = gridDim.x * blockDim.x;
    for (int i = blockIdx.x * blockDim.x + threadIdx.x; i < n4; i += stride) {
        float4 v = in[i];
        ushort4 o;
        o.x = f2bf(v.x); o.y = f2bf(v.y); o.z = f2bf(v.z); o.w = f2bf(v.w);
        out[i] = o;
    }
}

__global__ __launch_bounds__(256) void transpose_cvt_kernel(
    const float* __restrict__ W0, const float* __restrict__ W1,
    const float* __restrict__ W2, const float* __restrict__ W3,
    unsigned short* __restrict__ T0, unsigned short* __restrict__ T1,
    unsigned short* __restrict__ T2, unsigned short* __restrict__ T3)
{
    __shared__ float tile[32][33];
    const float* W; unsigned short* Wt;
    switch (blockIdx.z) {
        case 0: W = W0; Wt = T0; break;
        case 1: W = W1; Wt = T1; break;
        case 2: W = W2; Wt = T2; break;
        default: W = W3; Wt = T3; break;
    }
    const int tx = threadIdx.x, ty = threadIdx.y;     // 32 x 8
    const int n0 = blockIdx.x * 32, k0 = blockIdx.y * 32;
    #pragma unroll
    for (int i = 0; i < 4; i++)
        tile[ty + i * 8][tx] = W[(size_t)(k0 + ty + i * 8) * C_SZ + n0 + tx];
    __syncthreads();
    #pragma unroll
    for (int i = 0; i < 4; i++)
        Wt[(size_t)(n0 + ty + i * 8) * C_SZ + k0 + tx] = f2bf(tile[tx][ty + i * 8]);
}

// ---------------- GEMM core (m97 structure: 128x128 tile, BK=32) ----------------
// A: M x K row-major bf16.  Bt: N x K row-major bf16 (i.e. B transposed).
// 4 waves in 2x2, each wave computes 64x64 via 4x4 frags of 16x16x32 MFMA.

__device__ __forceinline__ void gemm_tile_core(
    const unsigned short* __restrict__ A,
    const unsigned short* __restrict__ Bt,
    unsigned short* As, unsigned short* Bs,
    int m0, int n0, f32x4 acc[4][4])
{
    const int tid = threadIdx.x;
    const int lane = tid & 63;
    const int w = tid >> 6;
    const int l15 = lane & 15, lg = lane >> 4;
    const int wr = (w >> 1) * 64, wc = (w & 1) * 64;

    // staging addresses: lane covers 16B = 8 bf16; row = tid>>2, kslot = tid&3
    const unsigned short* Ag0 = A + (size_t)(m0 + (tid >> 2)) * C_SZ + (tid & 3) * 8;
    const unsigned short* Ag1 = Ag0 + (size_t)64 * C_SZ;
    const unsigned short* Bg0 = Bt + (size_t)(n0 + (tid >> 2)) * C_SZ + (tid & 3) * 8;
    const unsigned short* Bg1 = Bg0 + (size_t)64 * C_SZ;
    unsigned short* As0 = As + w * 512;           // wave-uniform LDS dest (ushort units)
    unsigned short* As1 = As + 2048 + w * 512;
    unsigned short* Bs0 = Bs + w * 512;
    unsigned short* Bs1 = Bs + 2048 + w * 512;

    for (int k0 = 0; k0 < C_SZ; k0 += 32) {
        load_lds16(Ag0 + k0, As0);
        load_lds16(Ag1 + k0, As1);
        load_lds16(Bg0 + k0, Bs0);
        load_lds16(Bg1 + k0, Bs1);
        __syncthreads();   // emits vmcnt(0) drain + barrier
        bf16x8 af[4], bfv[4];
        const bf16x8* Ap = (const bf16x8*)As;
        const bf16x8* Bp = (const bf16x8*)Bs;
        #pragma unroll
        for (int m = 0; m < 4; m++) af[m] = Ap[(wr + m * 16 + l15) * 4 + lg];
        #pragma unroll
        for (int n = 0; n < 4; n++) bfv[n] = Bp[(wc + n * 16 + l15) * 4 + lg];
        #pragma unroll
        for (int m = 0; m < 4; m++)
            #pragma unroll
            for (int n = 0; n < 4; n++)
                acc[m][n] = __builtin_amdgcn_mfma_f32_16x16x32_bf16(af[m], bfv[n], acc[m][n], 0, 0, 0);
        __syncthreads();   // protect LDS before next stage
    }
}

// QKV projection GEMM. gridDim.z in {0,1,2} selects Q/K/V.
// Output layout (B,H,T,D) bf16; Q gets scale 0.125*log2(e) folded in.
__global__ __launch_bounds__(256) void gemm_qkv_kernel(
    const unsigned short* __restrict__ A,
    const unsigned short* __restrict__ WtBase,
    const float* __restrict__ bq, const float* __restrict__ bk, const float* __restrict__ bv,
    unsigned short* __restrict__ QKV)
{
    __shared__ unsigned short As[4096], Bs[4096];
    const int z = blockIdx.z;
    const unsigned short* Bt = WtBase + (size_t)z * CC;
    const float* bias = (z == 0) ? bq : (z == 1) ? bk : bv;
    const float scale = (z == 0) ? 0.18033688011112042f : 1.0f;  // 0.125 * log2(e)
    unsigned short* Out = QKV + (size_t)z * BHTD;

    f32x4 acc[4][4];
    f32x4 zero4 = {0.f, 0.f, 0.f, 0.f};
    #pragma unroll
    for (int m = 0; m < 4; m++)
        #pragma unroll
        for (int n = 0; n < 4; n++) acc[m][n] = zero4;

    const int m0 = blockIdx.y * 128, n0 = blockIdx.x * 128;
    gemm_tile_core(A, Bt, As, Bs, m0, n0, acc);

    const int lane = threadIdx.x & 63;
    const int w = threadIdx.x >> 6;
    const int l15 = lane & 15, lg = lane >> 4;
    const int wr = (w >> 1) * 64, wc = (w & 1) * 64;
    #pragma unroll
    for (int n = 0; n < 4; n++) {
        const int col = n0 + wc + n * 16 + l15;
        const float bias_v = bias[col];
        const int h = col >> 6, d = col & 63;
        #pragma unroll
        for (int m = 0; m < 4; m++) {
            #pragma unroll
            for (int j = 0; j < 4; j++) {
                const int row = m0 + wr + m * 16 + lg * 4 + j;   // global M row = b*T + t
                const int b = row >> 11, t = row & (T_SZ - 1);
                Out[(((size_t)(b * H_SZ + h)) * T_SZ + t) * D_SZ + d] =
                    f2bf((acc[m][n][j] + bias_v) * scale);
            }
        }
    }
}

// Output projection GEMM: O(bf16, M x C) @ Wo^T + bo -> f32 (B,T,C).
__global__ __launch_bounds__(256) void gemm_out_kernel(
    const unsigned short* __restrict__ A,
    const unsigned short* __restrict__ Bt,
    const float* __restrict__ bo,
    float* __restrict__ Out)
{
    __shared__ unsigned short As[4096], Bs[4096];
    f32x4 acc[4][4];
    f32x4 zero4 = {0.f, 0.f, 0.f, 0.f};
    #pragma unroll
    for (int m = 0; m < 4; m++)
        #pragma unroll
        for (int n = 0; n < 4; n++) acc[m][n] = zero4;

    const int m0 = blockIdx.y * 128, n0 = blockIdx.x * 128;
    gemm_tile_core(A, Bt, As, Bs, m0, n0, acc);

    const int lane = threadIdx.x & 63;
    const int w = threadIdx.x >> 6;
    const int l15 = lane & 15, lg = lane >> 4;
    const int wr = (w >> 1) * 64, wc = (w & 1) * 64;
    #pragma unroll
    for (int n = 0; n < 4; n++) {
        const int col = n0 + wc + n * 16 + l15;
        const float bias_v = bo[col];
        #pragma unroll
        for (int m = 0; m < 4; m++) {
            #pragma unroll
            for (int j = 0; j < 4; j++) {
                const int row = m0 + wr + m * 16 + lg * 4 + j;
                Out[(size_t)row * C_SZ + col] = acc[m][n][j] + bias_v;
            }
        }
    }
}

// ---------------- flash attention ----------------
// grid (T/64, B*H), block 256. Wave w owns q rows [q0 + w*16, +16).
// Q pre-scaled by 0.125*log2(e) -> softmax via exp2f.
// S = Q K^T via mfma(q_frag, k_frag): K rows load in A-fragment layout = B-frag of K^T.
// P transposed to A-layout through per-wave LDS buffer; V b-frags gathered from global (L2-resident).
__global__ __launch_bounds__(256) void attn_fwd_kernel(
    const unsigned short* __restrict__ Q,
    const unsigned short* __restrict__ K,
    const unsigned short* __restrict__ V,
    unsigned short* __restrict__ O)
{
    const int bh = blockIdx.y;
    const int w = threadIdx.x >> 6;
    const int lane = threadIdx.x & 63;
    const int l15 = lane & 15, lg = lane >> 4;
    const int qb = blockIdx.x * 64 + w * 16;

    const unsigned short* Qh = Q + (size_t)bh * T_SZ * D_SZ;
    const unsigned short* Kh = K + (size_t)bh * T_SZ * D_SZ;
    const unsigned short* Vh = V + (size_t)bh * T_SZ * D_SZ;

    __shared__ unsigned short P_lds[4][16 * 32];   // per-wave P transpose buffer
    unsigned short* pl = &P_lds[w][0];

    const bf16x8 qf0 = *(const bf16x8*)&Qh[(size_t)(qb + l15) * D_SZ + lg * 8];
    const bf16x8 qf1 = *(const bf16x8*)&Qh[(size_t)(qb + l15) * D_SZ + 32 + lg * 8];

    f32x4 zero4 = {0.f, 0.f, 0.f, 0.f};
    f32x4 acc[4];
    #pragma unroll
    for (int c = 0; c < 4; c++) acc[c] = zero4;
    float mrun[4], lrun[4];
    #pragma unroll
    for (int j = 0; j < 4; j++) { mrun[j] = -3.0e38f; lrun[j] = 0.f; }

    const int ntiles = (qb + 47) >> 5;   // cover kv rows up to qb+15
    for (int t = 0; t < ntiles; t++) {
        const int k0 = t * 32;
        // ---- S = Q K^T (16q x 32kv) ----
        f32x4 s[2];
        #pragma unroll
        for (int col = 0; col < 2; col++) {
            const unsigned short* kr = &Kh[(size_t)(k0 + col * 16 + l15) * D_SZ + lg * 8];
            bf16x8 kf0 = *(const bf16x8*)kr;
            bf16x8 kf1 = *(const bf16x8*)(kr + 32);
            f32x4 sc = zero4;
            sc = __builtin_amdgcn_mfma_f32_16x16x32_bf16(qf0, kf0, sc, 0, 0, 0);
            sc = __builtin_amdgcn_mfma_f32_16x16x32_bf16(qf1, kf1, sc, 0, 0, 0);
            s[col] = sc;
        }
        // ---- causal mask (only diagonal tiles) ----
        if (k0 + 31 > qb) {
            #pragma unroll
            for (int col = 0; col < 2; col++) {
                const int kc = k0 + col * 16 + l15;
                #pragma unroll
                for (int j = 0; j < 4; j++) {
                    const int qr = qb + lg * 4 + j;
                    s[col][j] = (kc > qr) ? -3.0e38f : s[col][j];
                }
            }
        }
        // ---- online softmax (wave-parallel 16-lane reduce) ----
        float alpha[4];
        #pragma unroll
        for (int j = 0; j < 4; j++) {
            float rm = fmaxf(s[0][j], s[1][j]);
            rm = fmaxf(rm, __shfl_xor(rm, 1));
            rm = fmaxf(rm, __shfl_xor(rm, 2));
            rm = fmaxf(rm, __shfl_xor(rm, 4));
            rm = fmaxf(rm, __shfl_xor(rm, 8));
            const float mnew = fmaxf(mrun[j], rm);
            alpha[j] = exp2f(mrun[j] - mnew);
            mrun[j] = mnew;
            s[0][j] = exp2f(s[0][j] - mnew);
            s[1][j] = exp2f(s[1][j] - mnew);
            float rs = s[0][j] + s[1][j];
            rs += __shfl_xor(rs, 1);
            rs += __shfl_xor(rs, 2);
            rs += __shfl_xor(rs, 4);
            rs += __shfl_xor(rs, 8);
            lrun[j] = lrun[j] * alpha[j] + rs;
        }
        #pragma unroll
        for (int c = 0; c < 4; c++)
            #pragma unroll
            for (int j = 0; j < 4; j++)
                acc[c][j] *= alpha[j];
        // ---- P (C/D layout) -> LDS -> A-fragment layout ----
        #pragma unroll
        for (int col = 0; col < 2; col++)
            #pragma unroll
            for (int j = 0; j < 4; j++)
                pl[(lg * 4 + j) * 32 + col * 16 + l15] = f2bf(s[col][j]);
        const bf16x8 pa = *(const bf16x8*)&pl[l15 * 32 + lg * 8];
        // ---- O += P V ----
        #pragma unroll
        for (int c = 0; c < 4; c++) {
            const __bf16* vp = (const __bf16*)&Vh[(size_t)(k0 + lg * 8) * D_SZ + c * 16 + l15];
            bf16x8 vb;
            #pragma unroll
            for (int j = 0; j < 8; j++) vb[j] = vp[j * D_SZ];
            acc[c] = __builtin_amdgcn_mfma_f32_16x16x32_bf16(pa, vb, acc[c], 0, 0, 0);
        }
    }

    // ---- epilogue: O/l -> (B,T,C) bf16 ----
    const int b = bh >> 4, h = bh & 15;
    #pragma unroll
    for (int j = 0; j < 4; j++) {
        const float inv = 1.0f / lrun[j];
        const int trow = qb + lg * 4 + j;
        const size_t base = ((size_t)(b * T_SZ + trow)) * C_SZ + h * D_SZ;
        #pragma unroll
        for (int c = 0; c < 4; c++)
            O[base + c * 16 + l15] = f2bf(acc[c][j] * inv);
    }
}

// ---------------- launch ----------------

extern "C" void kernel_launch(void* const* d_in, const int* in_sizes, int n_in,
                              void* d_out, int out_size, void* d_ws, size_t ws_size,
                              hipStream_t stream)
{
    const float* x  = (const float*)d_in[0];
    const float* Wq = (const float*)d_in[1];
    const float* bq = (const float*)d_in[2];
    const float* Wk = (const float*)d_in[3];
    const float* bk = (const float*)d_in[4];
    const float* Wv = (const float*)d_in[5];
    const float* bv = (const float*)d_in[6];
    const float* Wo = (const float*)d_in[7];
    const float* bo = (const float*)d_in[8];

    uint8_t* ws = (uint8_t*)d_ws;
    unsigned short* XB  = (unsigned short*)(ws);                        // 8 MB
    unsigned short* WT  = (unsigned short*)(ws + (8u  << 20));          // 8 MB (q,k,v,o)
    unsigned short* QKV = (unsigned short*)(ws + (16u << 20));          // 24 MB
    unsigned short* OB  = (unsigned short*)(ws + (40u << 20));          // 8 MB

    cvt_x_kernel<<<2048, 256, 0, stream>>>((const float4*)x, (ushort4*)XB, M_SZ * C_SZ / 4);
    transpose_cvt_kernel<<<dim3(32, 32, 4), dim3(32, 8), 0, stream>>>(
        Wq, Wk, Wv, Wo, WT, WT + CC, WT + 2 * (size_t)CC, WT + 3 * (size_t)CC);
    gemm_qkv_kernel<<<dim3(8, 32, 3), 256, 0, stream>>>(XB, WT, bq, bk, bv, QKV);
    attn_fwd_kernel<<<dim3(32, 32), 256, 0, stream>>>(QKV, QKV + BHTD, QKV + 2 * (size_t)BHTD, OB);
    gemm_out_kernel<<<dim3(8, 32), 256, 0, stream>>>(OB, WT + 3 * (size_t)CC, bo, (float*)d_out);
}

// Round 2
// 195.819 us; speedup vs baseline: 1.2669x; 1.2669x over previous
//
#include <hip/hip_runtime.h>
#include <stdint.h>
#include <stddef.h>

// Causal attention fused layer for MI355X (gfx950).
// B=2 T=2048 C=1024 H=16 D=64.
// Pipeline: cvt x -> bf16 | transpose-cvt weights -> bf16 N*K | QKV GEMM (mfma 16x16x32 bf16)
//           | V transpose (B,H,D,T) | flash attention (4 waves, 32 q/wave, KV tile 64)
//           | out GEMM f32.
// Workspace layout (needs >= 48 MB):
//   [0,8MB)   x bf16            (M=4096 x K=1024)
//   [8,16MB)  Wt q,k,v,o bf16   (4 x 1024x1024, transposed N x K)
//   [16,32MB) Q,K bf16          ((B,H,T,D)), Q pre-scaled by 0.125*log2(e)
//   [32,40MB) V^T bf16          ((B,H,D,T))
//   [40,48MB) Vtmp then O bf16  (V normal layout, overwritten by attn output (B,T,C))

#define B_SZ 2
#define T_SZ 2048
#define C_SZ 1024
#define H_SZ 16
#define D_SZ 64
#define M_SZ (B_SZ * T_SZ)              // 4096
#define BHTD (B_SZ * H_SZ * T_SZ * D_SZ) // 4194304
#define CC (C_SZ * C_SZ)                 // 1048576
#define PLD 72                           // P LDS row stride (ushorts): 16B-aligned rows, 2-way banks

typedef __attribute__((ext_vector_type(8))) __bf16 bf16x8;
typedef __attribute__((ext_vector_type(4))) float f32x4;

__device__ __forceinline__ unsigned short f2bf(float f) {
    union { float f; unsigned u; } v; v.f = f;
    v.u += 0x7fffu + ((v.u >> 16) & 1u);   // round-to-nearest-even
    return (unsigned short)(v.u >> 16);
}

__device__ __forceinline__ void load_lds16(const unsigned short* g, unsigned short* l) {
    // width=16 async global->LDS; LDS dest is wave-uniform base + lane*16.
    __builtin_amdgcn_global_load_lds(
        (const __attribute__((address_space(1))) void*)g,
        (__attribute__((address_space(3))) void*)l, 16, 0, 0);
}

// ---------------- conversion kernels ----------------

__global__ void cvt_x_kernel(const float4* __restrict__ in, ushort4* __restrict__ out, int n4) {
    int stride = gridDim.x * blockDim.x;
    for (int i = blockIdx.x * blockDim.x + threadIdx.x; i < n4; i += stride) {
        float4 v = in[i];
        ushort4 o;
        o.x = f2bf(v.x); o.y = f2bf(v.y); o.z = f2bf(v.z); o.w = f2bf(v.w);
        out[i] = o;
    }
}

__global__ __launch_bounds__(256) void transpose_cvt_kernel(
    const float* __restrict__ W0, const float* __restrict__ W1,
    const float* __restrict__ W2, const float* __restrict__ W3,
    unsigned short* __restrict__ T0, unsigned short* __restrict__ T1,
    unsigned short* __restrict__ T2, unsigned short* __restrict__ T3)
{
    __shared__ float tile[32][33];
    const float* W; unsigned short* Wt;
    switch (blockIdx.z) {
        case 0: W = W0; Wt = T0; break;
        case 1: W = W1; Wt = T1; break;
        case 2: W = W2; Wt = T2; break;
        default: W = W3; Wt = T3; break;
    }
    const int tx = threadIdx.x, ty = threadIdx.y;     // 32 x 8
    const int n0 = blockIdx.x * 32, k0 = blockIdx.y * 32;
    #pragma unroll
    for (int i = 0; i < 4; i++)
        tile[ty + i * 8][tx] = W[(size_t)(k0 + ty + i * 8) * C_SZ + n0 + tx];
    __syncthreads();
    #pragma unroll
    for (int i = 0; i < 4; i++)
        Wt[(size_t)(n0 + ty + i * 8) * C_SZ + k0 + tx] = f2bf(tile[tx][ty + i * 8]);
}

// V (B,H,T,D) -> V^T (B,H,D,T), per-head 2048x64 transpose in 32x32 tiles.
__global__ __launch_bounds__(256) void vt_kernel(
    const unsigned short* __restrict__ V, unsigned short* __restrict__ Vt)
{
    __shared__ unsigned short tile[32][33];
    const int bh = blockIdx.z;
    const int t0 = blockIdx.x * 32, d0 = blockIdx.y * 32;
    const unsigned short* src = V + (size_t)bh * T_SZ * D_SZ;
    unsigned short* dst = Vt + (size_t)bh * T_SZ * D_SZ;
    const int tx = threadIdx.x, ty = threadIdx.y;     // 32 x 8
    #pragma unroll
    for (int i = 0; i < 4; i++)
        tile[ty + i * 8][tx] = src[(size_t)(t0 + ty + i * 8) * D_SZ + d0 + tx];
    __syncthreads();
    #pragma unroll
    for (int i = 0; i < 4; i++)
        dst[(size_t)(d0 + ty + i * 8) * T_SZ + t0 + tx] = tile[tx][ty + i * 8];
}

// ---------------- GEMM core (m97 structure: 128x128 tile, BK=32) ----------------

__device__ __forceinline__ void gemm_tile_core(
    const unsigned short* __restrict__ A,
    const unsigned short* __restrict__ Bt,
    unsigned short* As, unsigned short* Bs,
    int m0, int n0, f32x4 acc[4][4])
{
    const int tid = threadIdx.x;
    const int lane = tid & 63;
    const int w = tid >> 6;
    const int l15 = lane & 15, lg = lane >> 4;
    const int wr = (w >> 1) * 64, wc = (w & 1) * 64;

    const unsigned short* Ag0 = A + (size_t)(m0 + (tid >> 2)) * C_SZ + (tid & 3) * 8;
    const unsigned short* Ag1 = Ag0 + (size_t)64 * C_SZ;
    const unsigned short* Bg0 = Bt + (size_t)(n0 + (tid >> 2)) * C_SZ + (tid & 3) * 8;
    const unsigned short* Bg1 = Bg0 + (size_t)64 * C_SZ;
    unsigned short* As0 = As + w * 512;
    unsigned short* As1 = As + 2048 + w * 512;
    unsigned short* Bs0 = Bs + w * 512;
    unsigned short* Bs1 = Bs + 2048 + w * 512;

    for (int k0 = 0; k0 < C_SZ; k0 += 32) {
        load_lds16(Ag0 + k0, As0);
        load_lds16(Ag1 + k0, As1);
        load_lds16(Bg0 + k0, Bs0);
        load_lds16(Bg1 + k0, Bs1);
        __syncthreads();
        bf16x8 af[4], bfv[4];
        const bf16x8* Ap = (const bf16x8*)As;
        const bf16x8* Bp = (const bf16x8*)Bs;
        #pragma unroll
        for (int m = 0; m < 4; m++) af[m] = Ap[(wr + m * 16 + l15) * 4 + lg];
        #pragma unroll
        for (int n = 0; n < 4; n++) bfv[n] = Bp[(wc + n * 16 + l15) * 4 + lg];
        #pragma unroll
        for (int m = 0; m < 4; m++)
            #pragma unroll
            for (int n = 0; n < 4; n++)
                acc[m][n] = __builtin_amdgcn_mfma_f32_16x16x32_bf16(af[m], bfv[n], acc[m][n], 0, 0, 0);
        __syncthreads();
    }
}

// QKV projection GEMM. gridDim.z in {0,1,2} selects Q/K/V.
// Q,K -> (B,H,T,D) bf16 (Q scaled by 0.125*log2(e)); V -> Vtmp (B,H,T,D).
__global__ __launch_bounds__(256) void gemm_qkv_kernel(
    const unsigned short* __restrict__ A,
    const unsigned short* __restrict__ WtBase,
    const float* __restrict__ bq, const float* __restrict__ bk, const float* __restrict__ bv,
    unsigned short* __restrict__ QKV, unsigned short* __restrict__ Vtmp)
{
    __shared__ unsigned short As[4096], Bs[4096];
    const int z = blockIdx.z;
    const unsigned short* Bt = WtBase + (size_t)z * CC;
    const float* bias = (z == 0) ? bq : (z == 1) ? bk : bv;
    const float scale = (z == 0) ? 0.18033688011112042f : 1.0f;  // 0.125 * log2(e)
    unsigned short* Out = (z == 2) ? Vtmp : QKV + (size_t)z * BHTD;

    f32x4 acc[4][4];
    f32x4 zero4 = {0.f, 0.f, 0.f, 0.f};
    #pragma unroll
    for (int m = 0; m < 4; m++)
        #pragma unroll
        for (int n = 0; n < 4; n++) acc[m][n] = zero4;

    const int m0 = blockIdx.y * 128, n0 = blockIdx.x * 128;
    gemm_tile_core(A, Bt, As, Bs, m0, n0, acc);

    const int lane = threadIdx.x & 63;
    const int w = threadIdx.x >> 6;
    const int l15 = lane & 15, lg = lane >> 4;
    const int wr = (w >> 1) * 64, wc = (w & 1) * 64;
    #pragma unroll
    for (int n = 0; n < 4; n++) {
        const int col = n0 + wc + n * 16 + l15;
        const float bias_v = bias[col];
        const int h = col >> 6, d = col & 63;
        #pragma unroll
        for (int m = 0; m < 4; m++) {
            #pragma unroll
            for (int j = 0; j < 4; j++) {
                const int row = m0 + wr + m * 16 + lg * 4 + j;   // global M row = b*T + t
                const int b = row >> 11, t = row & (T_SZ - 1);
                Out[(((size_t)(b * H_SZ + h)) * T_SZ + t) * D_SZ + d] =
                    f2bf((acc[m][n][j] + bias_v) * scale);
            }
        }
    }
}

// Output projection GEMM: O(bf16, M x C) @ Wo^T + bo -> f32 (B,T,C).
__global__ __launch_bounds__(256) void gemm_out_kernel(
    const unsigned short* __restrict__ A,
    const unsigned short* __restrict__ Bt,
    const float* __restrict__ bo,
    float* __restrict__ Out)
{
    __shared__ unsigned short As[4096], Bs[4096];
    f32x4 acc[4][4];
    f32x4 zero4 = {0.f, 0.f, 0.f, 0.f};
    #pragma unroll
    for (int m = 0; m < 4; m++)
        #pragma unroll
        for (int n = 0; n < 4; n++) acc[m][n] = zero4;

    const int m0 = blockIdx.y * 128, n0 = blockIdx.x * 128;
    gemm_tile_core(A, Bt, As, Bs, m0, n0, acc);

    const int lane = threadIdx.x & 63;
    const int w = threadIdx.x >> 6;
    const int l15 = lane & 15, lg = lane >> 4;
    const int wr = (w >> 1) * 64, wc = (w & 1) * 64;
    #pragma unroll
    for (int n = 0; n < 4; n++) {
        const int col = n0 + wc + n * 16 + l15;
        const float bias_v = bo[col];
        #pragma unroll
        for (int m = 0; m < 4; m++) {
            #pragma unroll
            for (int j = 0; j < 4; j++) {
                const int row = m0 + wr + m * 16 + lg * 4 + j;
                Out[(size_t)row * C_SZ + col] = acc[m][n][j] + bias_v;
            }
        }
    }
}

// ---------------- flash attention ----------------
// grid (T/128, B*H), block 256. Wave w owns q rows [blockIdx.x*128 + w*32, +32).
// KV tile 64. Q pre-scaled by 0.125*log2(e) -> softmax via exp2f.
// S = Q K^T via mfma(q_frag, k_row_frag); V consumed from pre-transposed (B,H,D,T)
// so PV B-fragments are contiguous bf16x8 vector loads.
__global__ __launch_bounds__(256) void attn_fwd_kernel(
    const unsigned short* __restrict__ Q,
    const unsigned short* __restrict__ K,
    const unsigned short* __restrict__ Vt,
    unsigned short* __restrict__ O)
{
    const int bh = blockIdx.y;
    const int w = threadIdx.x >> 6;
    const int lane = threadIdx.x & 63;
    const int l15 = lane & 15, lg = lane >> 4;
    const int qb = blockIdx.x * 128 + w * 32;

    const unsigned short* Qh = Q + (size_t)bh * T_SZ * D_SZ;
    const unsigned short* Kh = K + (size_t)bh * T_SZ * D_SZ;
    const unsigned short* Vh = Vt + (size_t)bh * T_SZ * D_SZ;   // (D,T) layout

    __shared__ unsigned short P_lds[4][32 * PLD];   // per-wave P transpose buffer
    unsigned short* pl = &P_lds[w][0];
    __bf16* plb = (__bf16*)pl;

    // Q fragments: 2 row-frags x 2 K-halves
    bf16x8 qf[2][2];
    #pragma unroll
    for (int m = 0; m < 2; m++)
        #pragma unroll
        for (int half = 0; half < 2; half++)
            qf[m][half] = *(const bf16x8*)&Qh[(size_t)(qb + m * 16 + l15) * D_SZ + half * 32 + lg * 8];

    f32x4 zero4 = {0.f, 0.f, 0.f, 0.f};
    f32x4 acc[2][4];
    #pragma unroll
    for (int m = 0; m < 2; m++)
        #pragma unroll
        for (int c = 0; c < 4; c++) acc[m][c] = zero4;
    float mrun[2][4], lrun[2][4];
    #pragma unroll
    for (int m = 0; m < 2; m++)
        #pragma unroll
        for (int j = 0; j < 4; j++) { mrun[m][j] = -3.0e38f; lrun[m][j] = 0.f; }

    const int ntiles = (qb + 95) >> 6;   // last tile start k0 <= qb: no all-masked rows
    for (int t = 0; t < ntiles; t++) {
        const int k0 = t * 64;
        // ---- S = Q K^T (32q x 64kv) ----
        f32x4 s[2][4];
        #pragma unroll
        for (int col = 0; col < 4; col++) {
            const unsigned short* kr = &Kh[(size_t)(k0 + col * 16 + l15) * D_SZ + lg * 8];
            bf16x8 kf0 = *(const bf16x8*)kr;
            bf16x8 kf1 = *(const bf16x8*)(kr + 32);
            #pragma unroll
            for (int m = 0; m < 2; m++) {
                f32x4 sc = __builtin_amdgcn_mfma_f32_16x16x32_bf16(qf[m][0], kf0, zero4, 0, 0, 0);
                s[m][col] = __builtin_amdgcn_mfma_f32_16x16x32_bf16(qf[m][1], kf1, sc, 0, 0, 0);
            }
        }
        // ---- causal mask (only tiles overlapping the diagonal) ----
        if (k0 + 63 > qb) {
            #pragma unroll
            for (int col = 0; col < 4; col++) {
                const int kc = k0 + col * 16 + l15;
                #pragma unroll
                for (int m = 0; m < 2; m++)
                    #pragma unroll
                    for (int j = 0; j < 4; j++) {
                        const int qr = qb + m * 16 + lg * 4 + j;
                        s[m][col][j] = (kc > qr) ? -3.0e38f : s[m][col][j];
                    }
            }
        }
        // ---- online softmax (16-lane shfl reduce over l15) ----
        float alpha[2][4];
        #pragma unroll
        for (int m = 0; m < 2; m++)
            #pragma unroll
            for (int j = 0; j < 4; j++) {
                float rm = fmaxf(fmaxf(s[m][0][j], s[m][1][j]), fmaxf(s[m][2][j], s[m][3][j]));
                rm = fmaxf(rm, __shfl_xor(rm, 1));
                rm = fmaxf(rm, __shfl_xor(rm, 2));
                rm = fmaxf(rm, __shfl_xor(rm, 4));
                rm = fmaxf(rm, __shfl_xor(rm, 8));
                const float mnew = fmaxf(mrun[m][j], rm);
                const float a = exp2f(mrun[m][j] - mnew);
                alpha[m][j] = a;
                mrun[m][j] = mnew;
                float rs = 0.f;
                #pragma unroll
                for (int col = 0; col < 4; col++) {
                    s[m][col][j] = exp2f(s[m][col][j] - mnew);
                    rs += s[m][col][j];
                }
                rs += __shfl_xor(rs, 1);
                rs += __shfl_xor(rs, 2);
                rs += __shfl_xor(rs, 4);
                rs += __shfl_xor(rs, 8);
                lrun[m][j] = lrun[m][j] * a + rs;
            }
        #pragma unroll
        for (int m = 0; m < 2; m++)
            #pragma unroll
            for (int c = 0; c < 4; c++)
                #pragma unroll
                for (int j = 0; j < 4; j++)
                    acc[m][c][j] *= alpha[m][j];
        // ---- P (C/D layout) -> LDS -> A-fragment layout ----
        #pragma unroll
        for (int m = 0; m < 2; m++)
            #pragma unroll
            for (int col = 0; col < 4; col++)
                #pragma unroll
                for (int j = 0; j < 4; j++)
                    plb[(m * 16 + lg * 4 + j) * PLD + col * 16 + l15] = (__bf16)s[m][col][j];
        bf16x8 pa[2][2];
        #pragma unroll
        for (int m = 0; m < 2; m++)
            #pragma unroll
            for (int ks = 0; ks < 2; ks++)
                pa[m][ks] = *(const bf16x8*)&pl[(m * 16 + l15) * PLD + ks * 32 + lg * 8];
        // ---- O += P V (V^T rows are contiguous in t) ----
        #pragma unroll
        for (int ks = 0; ks < 2; ks++)
            #pragma unroll
            for (int c = 0; c < 4; c++) {
                const bf16x8 vb = *(const bf16x8*)&Vh[(size_t)(c * 16 + l15) * T_SZ + k0 + ks * 32 + lg * 8];
                acc[0][c] = __builtin_amdgcn_mfma_f32_16x16x32_bf16(pa[0][ks], vb, acc[0][c], 0, 0, 0);
                acc[1][c] = __builtin_amdgcn_mfma_f32_16x16x32_bf16(pa[1][ks], vb, acc[1][c], 0, 0, 0);
            }
    }

    // ---- epilogue: O/l -> (B,T,C) bf16 ----
    const int b = bh >> 4, h = bh & 15;
    #pragma unroll
    for (int m = 0; m < 2; m++)
        #pragma unroll
        for (int j = 0; j < 4; j++) {
            const float inv = 1.0f / lrun[m][j];
            const int trow = qb + m * 16 + lg * 4 + j;
            const size_t base = ((size_t)(b * T_SZ + trow)) * C_SZ + h * D_SZ;
            #pragma unroll
            for (int c = 0; c < 4; c++)
                O[base + c * 16 + l15] = f2bf(acc[m][c][j] * inv);
        }
}

// ---------------- launch ----------------

extern "C" void kernel_launch(void* const* d_in, const int* in_sizes, int n_in,
                              void* d_out, int out_size, void* d_ws, size_t ws_size,
                              hipStream_t stream)
{
    const float* x  = (const float*)d_in[0];
    const float* Wq = (const float*)d_in[1];
    const float* bq = (const float*)d_in[2];
    const float* Wk = (const float*)d_in[3];
    const float* bk = (const float*)d_in[4];
    const float* Wv = (const float*)d_in[5];
    const float* bv = (const float*)d_in[6];
    const float* Wo = (const float*)d_in[7];
    const float* bo = (const float*)d_in[8];

    uint8_t* ws = (uint8_t*)d_ws;
    unsigned short* XB   = (unsigned short*)(ws);                        // 8 MB
    unsigned short* WT   = (unsigned short*)(ws + (8u  << 20));          // 8 MB (q,k,v,o)
    unsigned short* QKV  = (unsigned short*)(ws + (16u << 20));          // Q, K, V^T (24 MB)
    unsigned short* Vtmp = (unsigned short*)(ws + (40u << 20));          // V staging, then attn O

    cvt_x_kernel<<<2048, 256, 0, stream>>>((const float4*)x, (ushort4*)XB, M_SZ * C_SZ / 4);
    transpose_cvt_kernel<<<dim3(32, 32, 4), dim3(32, 8), 0, stream>>>(
        Wq, Wk, Wv, Wo, WT, WT + CC, WT + 2 * (size_t)CC, WT + 3 * (size_t)CC);
    gemm_qkv_kernel<<<dim3(8, 32, 3), 256, 0, stream>>>(XB, WT, bq, bk, bv, QKV, Vtmp);
    vt_kernel<<<dim3(64, 2, 32), dim3(32, 8), 0, stream>>>(Vtmp, QKV + 2 * (size_t)BHTD);
    attn_fwd_kernel<<<dim3(16, 32), 256, 0, stream>>>(
        QKV, QKV + BHTD, QKV + 2 * (size_t)BHTD, Vtmp);
    gemm_out_kernel<<<dim3(8, 32), 256, 0, stream>>>(Vtmp, WT + 3 * (size_t)CC, bo, (float*)d_out);
}